// Round 5
// baseline (1192.157 us; speedup 1.0000x reference)
//
#include <hip/hip_runtime.h>
#include <hip/hip_bf16.h>

#define NT 1024
#define NNODES 4096
#define ECAP 65536   // max arcs after iteration-1 symmetrization (E0 <= 32768)

// raw workgroup barrier: drain LDS ops only (no vmcnt) — main-loop global ops
// are read-only (OTH) or write-only-until-kernel-end (NBR), so vmcnt(0) is
// semantically unnecessary; __syncthreads would drain it every iteration.
#define BAR_LDS() asm volatile("s_waitcnt lgkmcnt(0)\n\ts_barrier" ::: "memory")

// ---------------- block-wide exclusive scan over NT=1024 values ----------------
__device__ __forceinline__ int blockScanExcl(int v, int* s_w, int* total) {
    const int tid  = threadIdx.x;
    const int lane = tid & 63;
    const int wv   = tid >> 6;
    int x = v;
#pragma unroll
    for (int off = 1; off < 64; off <<= 1) {
        int t = __shfl_up(x, off, 64);
        if (lane >= off) x += t;
    }
    if (lane == 63) s_w[wv] = x;
    __syncthreads();
    if (tid < 16) {
        int y = s_w[tid];
#pragma unroll
        for (int off = 1; off < 16; off <<= 1) {
            int t = __shfl_up(y, off, 16);
            if (tid >= off) y += t;
        }
        s_w[tid] = y;
    }
    __syncthreads();
    int base = wv ? s_w[wv - 1] : 0;
    int tot  = s_w[15];
    __syncthreads();   // protect s_w reuse
    *total = tot;
    return base + x - v;   // exclusive prefix
}

// ---------------- Phase A: full coarsening, single block ----------------
// s_bc slots: 0=node 2=nbrCnt 4=orderBase 7=maxdeg 9=not64
__global__ __launch_bounds__(NT, 1)
void phaseA(const int* __restrict__ ei, int E0,
            int* __restrict__ U, int* __restrict__ V,
            unsigned int* __restrict__ BM,
            int* __restrict__ NBR, int* __restrict__ OTH,
            int* __restrict__ SEL, int* __restrict__ CNTS,
            int* __restrict__ NST, int* __restrict__ FIL, int* __restrict__ SC,
            float* __restrict__ out)
{
    __shared__ unsigned short s_ordvis[NNODES];   // visbit(0x8000) | node id
    __shared__ unsigned short s_pos[NNODES];      // inverse permutation of order
    __shared__ unsigned char  s_sel[NNODES];
    __shared__ unsigned int   s_hb[NNODES / 32];  // iter-0 dedup bitmap
    __shared__ unsigned short s_so[NNODES];       // selection order
    __shared__ int s_cnt32[NNODES];               // per-iteration |H_k|
    __shared__ int s_roff[NNODES];                // CSR row start
    __shared__ int s_rend[NNODES];                // CSR row end
    __shared__ int s_tmp[NNODES];                 // deg / iter-0 stage / rank
    __shared__ unsigned short s_lab[NNODES];      // lazy label (chain length <= 1)
    __shared__ int s_stamp[NNODES];               // per-iteration dedup epoch
    __shared__ int s_w[16];
    __shared__ int s_bc[16];

    const int tid = threadIdx.x;
    const int ln  = tid & 63;

    for (int i = tid; i < NNODES; i += NT) {
        s_sel[i] = 0; s_tmp[i] = 0; s_stamp[i] = 0; s_cnt32[i] = 0;
    }
    for (int i = tid; i < NNODES / 32; i += NT) s_hb[i] = 0;
    if (tid < 16) s_bc[tid] = 0;
    __syncthreads();

    // ---- detect int64 vs int32 edge buffer (high words all zero => int64) ----
    for (int i = tid; i < E0; i += NT)
        if (ei[2 * i + 1] != 0) s_bc[9] = 1;
    __syncthreads();
    const int is64 = !s_bc[9];

    // ---- copy edges + degree histogram (I+O) ----
    for (int e = tid; e < E0; e += NT) {
        int uu = ei[is64 ? 2 * e : e];
        int vv = ei[is64 ? 2 * (E0 + e) : (E0 + e)];
        U[e] = uu; V[e] = vv;
        atomicAdd(&s_tmp[uu], 1);
        atomicAdd(&s_tmp[vv], 1);
    }
    __syncthreads();
    for (int n = tid; n < NNODES; n += NT) atomicMax(&s_bc[7], s_tmp[n]);
    __syncthreads();
    const int maxd = s_bc[7];

    // ---- stable argsort by descending degree (counting placement) ----
    for (int d = maxd; d >= 0; --d) {
        int n0 = tid * 4;
        int f0 = (s_tmp[n0] == d), f1 = (s_tmp[n0 + 1] == d);
        int f2 = (s_tmp[n0 + 2] == d), f3 = (s_tmp[n0 + 3] == d);
        int tot;
        int off = blockScanExcl(f0 + f1 + f2 + f3, s_w, &tot);
        int idx = s_bc[4] + off;
        if (f0) s_ordvis[idx++] = (unsigned short)n0;
        if (f1) s_ordvis[idx++] = (unsigned short)(n0 + 1);
        if (f2) s_ordvis[idx++] = (unsigned short)(n0 + 2);
        if (f3) s_ordvis[idx++] = (unsigned short)(n0 + 3);
        __syncthreads();
        if (tid == 0) s_bc[4] += tot;
        __syncthreads();
    }
    // ---- inverse permutation ----
    for (int i = tid; i < NNODES; i += NT) s_pos[(int)s_ordvis[i]] = (unsigned short)i;
    __syncthreads();

    // ================= iteration 0 (full-array scans, eager relabel) =================
    if (tid == 0) {
        int nd = (int)s_ordvis[0];
        s_bc[0] = nd; s_sel[nd] = 1;
        s_ordvis[0] = (unsigned short)(0x8000 | nd);   // mark hub visited
        s_so[0] = (unsigned short)nd;
    }
    __syncthreads();
    {
        const int node = s_bc[0];
        for (int e = tid; e < E0; e += NT) {
            int uu = U[e], vv = V[e];
            if (uu == node) {
                int w = vv; unsigned m = 1u << (w & 31);
                unsigned old = atomicOr(&s_hb[w >> 5], m);
                if (!(old & m)) {
                    int i = atomicAdd(&s_bc[2], 1); s_tmp[i] = w;
                    s_ordvis[s_pos[w]] = (unsigned short)(0x8000 | w);
                }
            }
            if (vv == node) {
                int w = uu; unsigned m = 1u << (w & 31);
                unsigned old = atomicOr(&s_hb[w >> 5], m);
                if (!(old & m)) {
                    int i = atomicAdd(&s_bc[2], 1); s_tmp[i] = w;
                    s_ordvis[s_pos[w]] = (unsigned short)(0x8000 | w);
                }
            }
        }
        __syncthreads();
        if (tid == 0) s_cnt32[0] = s_bc[2];
        // eager relabel Hn = H \ {node} (U/V frozen after this iteration)
        for (int e = tid; e < E0; e += NT) {
            int uu = U[e];
            if (uu != node && ((s_hb[uu >> 5] >> (uu & 31)) & 1)) U[e] = node;
            int vv = V[e];
            if (vv != node && ((s_hb[vv >> 5] >> (vv & 31)) & 1)) V[e] = node;
        }
        __syncthreads();
    }

    // ---- symmetry append (only iteration ever needing it), single-scan chunked ----
    {
        uint4* bm4 = (uint4*)BM;
        for (int i = tid; i < (1 << 17); i += NT) bm4[i] = make_uint4(0, 0, 0, 0);
    }
    __syncthreads();
    for (int e = tid; e < E0; e += NT) {
        int uu = U[e], vv = V[e];
        if (uu != vv) {
            unsigned code = ((unsigned)uu << 12) | (unsigned)vv;
            atomicOr(&BM[code >> 5], 1u << (code & 31));
        }
    }
    __syncthreads();
    int E1;
    {
        const int chA = (E0 + NT - 1) / NT;           // <= 32
        const int begA = tid * chA;
        unsigned long long mA = 0ull;
        for (int j = 0; j < chA; ++j) {
            int e = begA + j;
            if (e < E0) {
                int uu = U[e], vv = V[e];
                if (uu != vv) {
                    unsigned rc = ((unsigned)vv << 12) | (unsigned)uu;
                    unsigned old = atomicOr(&BM[rc >> 5], 0u);   // L2 read
                    if (!((old >> (rc & 31)) & 1u)) mA |= 1ull << j;
                }
            }
        }
        int tot;
        int off = blockScanExcl(__popcll(mA), s_w, &tot);
        for (int j = 0; j < chA; ++j) if ((mA >> j) & 1) {
            int e = begA + j;
            int r = off++;
            U[E0 + r] = V[e]; V[E0 + r] = U[e];
        }
        E1 = E0 + tot;
    }
    __syncthreads();

    // ---- build static CSR (other-endpoint only; BM region reused as OTH/NBR) ----
    for (int n = tid; n < NNODES; n += NT) s_roff[n] = 0;
    __syncthreads();
    for (int e = tid; e < E1; e += NT) {
        int uu = U[e], vv = V[e];
        if (uu != vv) { atomicAdd(&s_roff[uu], 1); atomicAdd(&s_roff[vv], 1); }
    }
    __syncthreads();
    {
        int n0 = tid * 4;
        int c0 = s_roff[n0], c1 = s_roff[n0 + 1], c2 = s_roff[n0 + 2], c3 = s_roff[n0 + 3];
        int tot;
        int off = blockScanExcl(c0 + c1 + c2 + c3, s_w, &tot);
        int st = off;
        s_roff[n0] = st;     s_rend[n0] = st;     st += c0;
        s_roff[n0 + 1] = st; s_rend[n0 + 1] = st; st += c1;
        s_roff[n0 + 2] = st; s_rend[n0 + 2] = st; st += c2;
        s_roff[n0 + 3] = st; s_rend[n0 + 3] = st;
    }
    __syncthreads();
    for (int e = tid; e < E1; e += NT) {
        int uu = U[e], vv = V[e];
        if (uu != vv) {
            int p = atomicAdd(&s_rend[uu], 1);
            int q = atomicAdd(&s_rend[vv], 1);
            OTH[p] = vv; OTH[q] = uu;
        }
    }
    __syncthreads();
    {   // flush iter-0 staged H into global NBR; init lazy labels to identity
        const int cnt0 = s_bc[2];
        for (int i = tid; i < cnt0; i += NT) NBR[i] = s_tmp[i];
    }
    for (int i = tid; i < NNODES; i += NT) s_lab[i] = (unsigned short)i;
    __syncthreads();   // full drain: CSR + NBR flush complete before main loop

    // ================= main loop: raw lgkm-only barrier, 1/iter =================
    int p = 0, k = 1;
    for (;;) {
        BAR_LDS();                              // iteration boundary (LDS visibility only)
        // ---- selection: every wave ballots the same 64-wide window of ordvis.
        //      Deterministic: marks are monotone, hub entry never marked, all
        //      H-members sit at positions after the hub. ----
        int node = -1;
        while (p < NNODES) {
            int idx = p + ln;
            int ov = (idx < NNODES) ? (int)s_ordvis[idx] : 0x8000;
            unsigned long long bal = __ballot(!(ov & 0x8000));
            if (bal != 0ull) {
                int sel = __ffsll(bal) - 1;
                node = __shfl(ov, sel, 64) & 0x7FFF;
                p += sel + 1;                   // window prefix permanently visited
                break;
            }
            p += 64;
        }
        if (node < 0) break;                    // uniform across waves
        if (tid == 0) { s_sel[node] = 1; s_so[k] = (unsigned short)node; }
        // ---- hub scan: static row + lazy label resolve + epoch-stamp dedup ----
        const int rb = s_roff[node], re = s_rend[node];
        for (int s0 = rb; s0 < re; s0 += NT) {  // uniform trip count
            int s = s0 + tid;
            bool isnew = false; int w = -1;
            if (s < re) {
                w = (int)s_lab[OTH[s]];
                if (w != node) {                // racy same-iter relabel: already counted
                    int old = atomicMax(&s_stamp[w], k);
                    isnew = old < k;
                }
            }
            unsigned long long b = __ballot(isnew);
            if (b != 0ull) {
                int cnt = __popcll(b);
                int before = __popcll(b & ((1ull << ln) - 1ull));
                int base = 0;
                if (isnew && before == 0) {     // wave leader
                    base = atomicAdd(&s_bc[2], cnt);
                    atomicAdd(&s_cnt32[k], cnt);
                }
                base = __shfl(base, __ffsll(b) - 1, 64);
                if (isnew) {
                    NBR[base + before] = w;
                    s_ordvis[s_pos[w]] = (unsigned short)(0x8000 | w);
                    if (!s_sel[w]) s_lab[w] = (unsigned short)node;   // absorb (chain <= 1)
                }
            }
        }
        k++;
    }
    const int K = k;
    __syncthreads();   // full drain before epilogue

    // ---- metadata: NST = exclusive prefix of CNTS (s_cnt32[i>=K] == 0) ----
    {
        int n0 = tid * 4;
        int c0 = s_cnt32[n0], c1 = s_cnt32[n0 + 1], c2 = s_cnt32[n0 + 2], c3 = s_cnt32[n0 + 3];
        int tot;
        int off = blockScanExcl(c0 + c1 + c2 + c3, s_w, &tot);
        if (n0 < K) {
            int st = off;
            if (n0     < K) { NST[n0]     = st; CNTS[n0]     = c0; } st += c0;
            if (n0 + 1 < K) { NST[n0 + 1] = st; CNTS[n0 + 1] = c1; } st += c1;
            if (n0 + 2 < K) { NST[n0 + 2] = st; CNTS[n0 + 2] = c2; } st += c2;
            if (n0 + 3 < K) { NST[n0 + 3] = st; CNTS[n0 + 3] = c3; }
        }
    }
    for (int i = tid; i < K; i += NT) SEL[i] = (int)s_so[i];
    if (tid == 0) {
        SC[0] = K;
        int f = 0;
        for (int i = 0; i < K; i++) { if (s_cnt32[i] > 0) f = i; FIL[i] = f; }
    }
    // ---- rank of each selected node among sorted(select) ----
    {
        int n0 = tid * 4;
        int r0 = s_sel[n0], r1 = s_sel[n0 + 1], r2 = s_sel[n0 + 2], r3 = s_sel[n0 + 3];
        int tot;
        int off = blockScanExcl(r0 + r1 + r2 + r3, s_w, &tot);
        int st = off;
        s_tmp[n0] = st;     st += r0;
        s_tmp[n0 + 1] = st; st += r1;
        s_tmp[n0 + 2] = st; st += r2;
        s_tmp[n0 + 3] = st;
    }
    __syncthreads();
    // ---- final stable compaction (single scan): resolve labels + remap + write ----
    {
        const int ch2 = (E1 + NT - 1) / NT;           // <= 64
        const int beg2 = tid * ch2;
        unsigned long long mF = 0ull;
        for (int j = 0; j < ch2; ++j) {
            int e = beg2 + j;
            if (e < E1) {
                int uu = (int)s_lab[U[e]], vv = (int)s_lab[V[e]];
                if (uu != vv) mF |= 1ull << j;
            }
        }
        int Ef;
        int off = blockScanExcl(__popcll(mF), s_w, &Ef);
        const size_t obase = (size_t)K * 8192;
        int r = off;
        for (int j = 0; j < ch2; ++j) if ((mF >> j) & 1) {
            int e = beg2 + j;
            out[obase + (size_t)r]             = (float)s_tmp[(int)s_lab[U[e]]];
            out[obase + (size_t)Ef + (size_t)r] = (float)s_tmp[(int)s_lab[V[e]]];
            r++;
        }
        if (tid == 0) SC[1] = Ef;
    }
}

// ---------------- Phase B: END rows (Dv | mean) with fill indirection ----------------
__global__ __launch_bounds__(256, 4)
void phaseB(const float* __restrict__ x,
            const float* __restrict__ W1, const float* __restrict__ W2,
            const float* __restrict__ B1, const float* __restrict__ B2,
            const int* __restrict__ NBR, const int* __restrict__ SEL,
            const int* __restrict__ CNTS, const int* __restrict__ NST,
            const int* __restrict__ FIL, const int* __restrict__ SC,
            float* __restrict__ out)
{
    const int K = SC[0];
    const int k = blockIdx.x;
    if (k >= K) return;
    const int kk   = FIL[k];
    const int node = SEL[kk];
    const int cnt  = CNTS[kk];
    const int st   = NST[kk];
    const int tid  = threadIdx.x;
    const float4* x4 = (const float4*)x;

    float4 acc[4];
#pragma unroll
    for (int j = 0; j < 4; j++) acc[j] = make_float4(0.f, 0.f, 0.f, 0.f);

    for (int r = 0; r < cnt; ++r) {
        const float4* row = x4 + (size_t)NBR[st + r] * 1024;
#pragma unroll
        for (int j = 0; j < 4; j++) {
            float4 t = row[tid + j * 256];
            acc[j].x += t.x; acc[j].y += t.y; acc[j].z += t.z; acc[j].w += t.w;
        }
    }

    const float fc  = (float)cnt;
    const float inv = 1.0f / (float)(cnt > 1 ? cnt : 1);
    const float4* xr = x4 + (size_t)node * 1024;
    float4* o4 = (float4*)(out + (size_t)k * 8192);

#pragma unroll
    for (int j = 0; j < 4; j++) {
        int c = tid + j * 256;
        float4 w1 = ((const float4*)W1)[c], b1 = ((const float4*)B1)[c];
        float4 w2 = ((const float4*)W2)[c], b2 = ((const float4*)B2)[c];
        float4 xv = xr[c];
        float4 pd, pm;
        pd.x = xv.x * w2.x + b2.x;
        pd.y = xv.y * w2.y + b2.y;
        pd.z = xv.z * w2.z + b2.z;
        pd.w = xv.w * w2.w + b2.w;
        pm.x = (acc[j].x * w1.x + fc * b1.x) * inv;
        pm.y = (acc[j].y * w1.y + fc * b1.y) * inv;
        pm.z = (acc[j].z * w1.z + fc * b1.z) * inv;
        pm.w = (acc[j].w * w1.w + fc * b1.w) * inv;
        o4[c] = pd;
        o4[1024 + c] = pm;
    }
}

extern "C" void kernel_launch(void* const* d_in, const int* in_sizes, int n_in,
                              void* d_out, int out_size, void* d_ws, size_t ws_size,
                              hipStream_t stream)
{
    const float* x  = (const float*)d_in[0];
    const int*   ei = (const int*)d_in[1];
    const float* W1 = (const float*)d_in[2];
    const float* W2 = (const float*)d_in[3];
    const float* B1 = (const float*)d_in[4];
    const float* B2 = (const float*)d_in[5];
    const int E0 = in_sizes[1] / 2;

    char* w = (char*)d_ws;
    int* U = (int*)w;                         // [ECAP]
    int* V = U + ECAP;                        // [ECAP]
    unsigned int* BM = (unsigned int*)(V + ECAP);   // 2 MB bitmap (iter-0 only)
    int* OTH = (int*)BM;                      // [2*ECAP] static CSR other-endpoint
    int* NBR = OTH + 2 * ECAP;                // [2*ECAP]
    char* meta = (char*)BM + (2u << 20);
    int* SEL  = (int*)meta;
    int* CNTS = SEL + NNODES;
    int* NST  = CNTS + NNODES;
    int* FIL  = NST + NNODES;
    int* SC   = FIL + NNODES;
    float* out = (float*)d_out;

    hipLaunchKernelGGL(phaseA, dim3(1), dim3(NT), 0, stream,
                       ei, E0, U, V, BM, NBR, OTH,
                       SEL, CNTS, NST, FIL, SC, out);
    hipLaunchKernelGGL(phaseB, dim3(NNODES), dim3(256), 0, stream,
                       x, W1, W2, B1, B2, NBR, SEL, CNTS, NST, FIL, SC, out);
}

// Round 6
// 965.867 us; speedup vs baseline: 1.2343x; 1.2343x over previous
//
#include <hip/hip_runtime.h>
#include <hip/hip_bf16.h>

#define NT 1024
#define NNODES 4096
#define ECAP 65536   // max arcs after iteration-1 symmetrization (E0 <= 32768)

// ---------------- block-wide exclusive scan over NT=1024 values ----------------
__device__ __forceinline__ int blockScanExcl(int v, int* s_w, int* total) {
    const int tid  = threadIdx.x;
    const int lane = tid & 63;
    const int wv   = tid >> 6;
    int x = v;
#pragma unroll
    for (int off = 1; off < 64; off <<= 1) {
        int t = __shfl_up(x, off, 64);
        if (lane >= off) x += t;
    }
    if (lane == 63) s_w[wv] = x;
    __syncthreads();
    if (tid < 16) {
        int y = s_w[tid];
#pragma unroll
        for (int off = 1; off < 16; off <<= 1) {
            int t = __shfl_up(y, off, 16);
            if (tid >= off) y += t;
        }
        s_w[tid] = y;
    }
    __syncthreads();
    int base = wv ? s_w[wv - 1] : 0;
    int tot  = s_w[15];
    __syncthreads();   // protect s_w reuse
    *total = tot;
    return base + x - v;   // exclusive prefix
}

// ================= Phase A1: preamble (R4-exact), dump handoff state =================
// s_bc slots: 0=node 2=nbrCnt 4=orderBase 5=appendBase 7=maxdeg 9=not64
__global__ __launch_bounds__(NT, 1)
void phaseA1(const int* __restrict__ ei, int E0,
             int* __restrict__ U, int* __restrict__ V,
             unsigned int* __restrict__ BM,
             int* __restrict__ NBR, int* __restrict__ OTH,
             int* __restrict__ ORDV, int* __restrict__ ROFFG, int* __restrict__ RENDG,
             int* __restrict__ HAND)
{
    __shared__ unsigned short s_order[NNODES];
    __shared__ unsigned char  s_vis[NNODES];
    __shared__ unsigned int   s_hb[NNODES / 32];
    __shared__ int s_roff[NNODES];
    __shared__ int s_rend[NNODES];
    __shared__ int s_tmp[NNODES];
    __shared__ int s_w[16];
    __shared__ int s_bc[16];

    const int tid = threadIdx.x;

    for (int i = tid; i < NNODES; i += NT) { s_vis[i] = 0; s_tmp[i] = 0; }
    for (int i = tid; i < NNODES / 32; i += NT) s_hb[i] = 0;
    if (tid < 16) s_bc[tid] = 0;
    __syncthreads();

    // ---- detect int64 vs int32 edge buffer ----
    for (int i = tid; i < E0; i += NT)
        if (ei[2 * i + 1] != 0) s_bc[9] = 1;
    __syncthreads();
    const int is64 = !s_bc[9];

    // ---- copy edges + degree histogram (I+O) ----
    for (int e = tid; e < E0; e += NT) {
        int uu = ei[is64 ? 2 * e : e];
        int vv = ei[is64 ? 2 * (E0 + e) : (E0 + e)];
        U[e] = uu; V[e] = vv;
        atomicAdd(&s_tmp[uu], 1);
        atomicAdd(&s_tmp[vv], 1);
    }
    __syncthreads();
    for (int n = tid; n < NNODES; n += NT) atomicMax(&s_bc[7], s_tmp[n]);
    __syncthreads();
    const int maxd = s_bc[7];

    // ---- stable argsort by descending degree ----
    for (int d = maxd; d >= 0; --d) {
        int n0 = tid * 4;
        int f0 = (s_tmp[n0] == d), f1 = (s_tmp[n0 + 1] == d);
        int f2 = (s_tmp[n0 + 2] == d), f3 = (s_tmp[n0 + 3] == d);
        int tot;
        int off = blockScanExcl(f0 + f1 + f2 + f3, s_w, &tot);
        int idx = s_bc[4] + off;
        if (f0) s_order[idx++] = (unsigned short)n0;
        if (f1) s_order[idx++] = (unsigned short)(n0 + 1);
        if (f2) s_order[idx++] = (unsigned short)(n0 + 2);
        if (f3) s_order[idx++] = (unsigned short)(n0 + 3);
        __syncthreads();
        if (tid == 0) s_bc[4] += tot;
        __syncthreads();
    }

    // ---- iteration 0 (full-array scans, eager relabel) ----
    if (tid == 0) {
        int nd = s_order[0];
        s_bc[0] = nd; s_vis[nd] = 1;
    }
    __syncthreads();
    {
        const int node = s_bc[0];
        for (int e = tid; e < E0; e += NT) {
            int uu = U[e], vv = V[e];
            if (uu == node) {
                int w = vv; unsigned m = 1u << (w & 31);
                unsigned old = atomicOr(&s_hb[w >> 5], m);
                if (!(old & m)) { int i = atomicAdd(&s_bc[2], 1); s_tmp[i] = w; s_vis[w] = 1; }
            }
            if (vv == node) {
                int w = uu; unsigned m = 1u << (w & 31);
                unsigned old = atomicOr(&s_hb[w >> 5], m);
                if (!(old & m)) { int i = atomicAdd(&s_bc[2], 1); s_tmp[i] = w; s_vis[w] = 1; }
            }
        }
        __syncthreads();
        // eager relabel Hn = H \ {node} (U/V frozen afterwards)
        for (int e = tid; e < E0; e += NT) {
            int uu = U[e];
            if (uu != node && ((s_hb[uu >> 5] >> (uu & 31)) & 1)) U[e] = node;
            int vv = V[e];
            if (vv != node && ((s_hb[vv >> 5] >> (vv & 31)) & 1)) V[e] = node;
        }
        __syncthreads();
    }

    // ---- symmetry append (only iteration ever needing it), R4 windowed ----
    for (int i = tid; i < (1 << 19); i += NT) BM[i] = 0u;
    __syncthreads();
    for (int e = tid; e < E0; e += NT) {
        int uu = U[e], vv = V[e];
        if (uu != vv) {
            unsigned code = ((unsigned)uu << 12) | (unsigned)vv;
            atomicOr(&BM[code >> 5], 1u << (code & 31));
        }
    }
    __syncthreads();
    for (int t = 0; t < E0; t += NT) {
        int e = t + tid, flag = 0, uu = 0, vv = 0;
        if (e < E0) {
            uu = U[e]; vv = V[e];
            if (uu != vv) {
                unsigned rc = ((unsigned)vv << 12) | (unsigned)uu;
                unsigned old = atomicOr(&BM[rc >> 5], 0u);   // L2 read
                flag = !((old >> (rc & 31)) & 1u);
            }
        }
        int tot;
        int off = blockScanExcl(flag, s_w, &tot);
        if (flag) { int r = s_bc[5] + off; U[E0 + r] = vv; V[E0 + r] = uu; }
        __syncthreads();
        if (tid == 0) s_bc[5] += tot;
        __syncthreads();
    }
    const int E1 = E0 + s_bc[5];

    // ---- build static CSR (other-endpoint only; BM region reused as OTH/NBR) ----
    for (int n = tid; n < NNODES; n += NT) s_roff[n] = 0;
    __syncthreads();
    for (int e = tid; e < E1; e += NT) {
        int uu = U[e], vv = V[e];
        if (uu != vv) { atomicAdd(&s_roff[uu], 1); atomicAdd(&s_roff[vv], 1); }
    }
    __syncthreads();
    {
        int n0 = tid * 4;
        int c0 = s_roff[n0], c1 = s_roff[n0 + 1], c2 = s_roff[n0 + 2], c3 = s_roff[n0 + 3];
        int tot;
        int off = blockScanExcl(c0 + c1 + c2 + c3, s_w, &tot);
        int st = off;
        s_roff[n0] = st;     s_rend[n0] = st;     st += c0;
        s_roff[n0 + 1] = st; s_rend[n0 + 1] = st; st += c1;
        s_roff[n0 + 2] = st; s_rend[n0 + 2] = st; st += c2;
        s_roff[n0 + 3] = st; s_rend[n0 + 3] = st;
    }
    __syncthreads();
    for (int e = tid; e < E1; e += NT) {
        int uu = U[e], vv = V[e];
        if (uu != vv) {
            int p = atomicAdd(&s_rend[uu], 1);
            int q = atomicAdd(&s_rend[vv], 1);
            OTH[p] = vv; OTH[q] = uu;
        }
    }
    __syncthreads();
    {   // flush iter-0 staged H into global NBR
        const int cnt0 = s_bc[2];
        for (int i = tid; i < cnt0; i += NT) NBR[i] = s_tmp[i];
    }
    // ---- dump handoff state ----
    for (int i = tid; i < NNODES; i += NT) {
        int nd = (int)s_order[i];
        ORDV[i]  = nd | (s_vis[nd] ? 0x8000 : 0);
        ROFFG[i] = s_roff[i];
        RENDG[i] = s_rend[i];
    }
    if (tid == 0) { HAND[0] = E1; HAND[1] = s_bc[2]; HAND[2] = s_bc[0]; }
}

// ================= Phase A2: main loop, SINGLE WAVE, zero barriers =================
__global__ __launch_bounds__(64, 1)
void phaseA2(const int* __restrict__ OTH, int* __restrict__ NBR,
             const int* __restrict__ ORDV, const int* __restrict__ ROFFG,
             const int* __restrict__ RENDG, const int* __restrict__ HAND,
             int* __restrict__ SEL, int* __restrict__ CNTS,
             int* __restrict__ NST, int* __restrict__ FIL, int* __restrict__ SC,
             int* __restrict__ LABG, int* __restrict__ RNKG)
{
    __shared__ unsigned short s_ordvis[NNODES];   // visbit(0x8000) | node id
    __shared__ unsigned short s_pos[NNODES];      // inverse permutation
    __shared__ unsigned short s_lab[NNODES];      // lazy label (chain <= 1)
    __shared__ unsigned short s_so[NNODES];       // selection order
    __shared__ int s_cnt[NNODES];                 // per-iteration |H_k|
    __shared__ int s_stamp[NNODES];               // dedup epoch; reused as rank
    __shared__ int s_roff[NNODES];
    __shared__ int s_rend[NNODES];
    __shared__ unsigned char s_sel[NNODES];
    __shared__ int s_nc[1];                       // NBR allocation cursor

    const int ln = threadIdx.x;                   // single wave: tid == lane
    const unsigned long long ltm = (1ull << ln) - 1ull;
    const int cnt0 = HAND[1], hub0 = HAND[2];

    for (int i = ln; i < NNODES; i += 64) {
        int ov = ORDV[i];
        s_ordvis[i] = (unsigned short)ov;
        s_pos[ov & 0x7FFF] = (unsigned short)i;
        s_roff[i] = ROFFG[i];
        s_rend[i] = RENDG[i];
        s_lab[i] = (unsigned short)i;
        s_stamp[i] = 0; s_sel[i] = 0; s_cnt[i] = 0;
    }
    if (ln == 0) {
        s_sel[hub0] = 1; s_so[0] = (unsigned short)hub0;
        s_cnt[0] = cnt0; s_nc[0] = cnt0;
    }
    // single wave: instruction order + lgkmcnt waits give LDS visibility; no barrier.

    // ---- main loop ----
    int p = 0, k = 1;
    for (;;) {
        // selection: one 64-wide window ballot per step (wave-uniform)
        int node = -1;
        while (p < NNODES) {
            int idx = p + ln;
            int ov = (idx < NNODES) ? (int)s_ordvis[idx] : 0x8000;
            unsigned long long bal = __ballot(!(ov & 0x8000));
            if (bal != 0ull) {
                int sl = __ffsll((long long)bal) - 1;
                node = __shfl(ov, sl, 64) & 0x7FFF;
                p += sl + 1;
                break;
            }
            p += 64;
        }
        if (node < 0) break;
        if (ln == 0) { s_sel[node] = 1; s_so[k] = (unsigned short)node; }
        const int rb = s_roff[node], re = s_rend[node];
        const int begin = s_nc[0];
        for (int s0 = rb; s0 < re; s0 += 128) {
            int sA = s0 + ln, sB = s0 + 64 + ln;
            int oA = (sA < re) ? OTH[sA] : -1;    // both loads issue together
            int oB = (sB < re) ? OTH[sB] : -1;
            if (oA >= 0) {
                int w = (int)s_lab[oA];
                if (w != node) {
                    int old = atomicMax(&s_stamp[w], k);
                    if (old < k) {
                        int i = atomicAdd(&s_nc[0], 1);
                        NBR[i] = w;
                        s_ordvis[s_pos[w]] = (unsigned short)(0x8000 | w);
                        if (!s_sel[w]) s_lab[w] = (unsigned short)node;
                    }
                }
            }
            if (oB >= 0) {
                int w = (int)s_lab[oB];
                if (w != node) {
                    int old = atomicMax(&s_stamp[w], k);
                    if (old < k) {
                        int i = atomicAdd(&s_nc[0], 1);
                        NBR[i] = w;
                        s_ordvis[s_pos[w]] = (unsigned short)(0x8000 | w);
                        if (!s_sel[w]) s_lab[w] = (unsigned short)node;
                    }
                }
            }
        }
        if (ln == 0) s_cnt[k] = s_nc[0] - begin;
        k++;
    }
    const int K = k;

    // ---- rank of selected nodes among sorted(select); store into s_stamp ----
    {
        int base = 0;
        for (int c = 0; c < NNODES / 64; ++c) {
            int n = c * 64 + ln;
            int f = s_sel[n];
            unsigned long long b = __ballot(f);
            s_stamp[n] = base + __popcll(b & ltm);
            base += __popcll(b);
        }
    }
    // ---- SEL / CNTS / NST (exclusive prefix of CNTS) ----
    {
        int nb = 0;
        for (int c = 0; c * 64 < K; ++c) {
            int i = c * 64 + ln;
            int cv = (i < K) ? s_cnt[i] : 0;
            int x = cv;
#pragma unroll
            for (int off = 1; off < 64; off <<= 1) {
                int t = __shfl_up(x, off, 64);
                if (ln >= off) x += t;
            }
            if (i < K) { NST[i] = nb + x - cv; CNTS[i] = cv; SEL[i] = (int)s_so[i]; }
            nb += __shfl(x, 63, 64);
        }
    }
    // ---- FIL forward-fill via ballot + clz ----
    {
        int carry = 0;
        for (int c = 0; c * 64 < K; ++c) {
            int i = c * 64 + ln;
            int f = (i < K) && (s_cnt[i] > 0);
            unsigned long long b = __ballot(f);
            unsigned long long m = b & ((ln == 63) ? ~0ull : ((1ull << (ln + 1)) - 1ull));
            int fil = m ? (c * 64 + 63 - __clzll(m)) : carry;
            if (i < K) FIL[i] = fil;
            carry = b ? (c * 64 + 63 - __clzll(b)) : carry;
        }
    }
    if (ln == 0) SC[0] = K;
    // ---- dump labels + ranks for A3 ----
    for (int i = ln; i < NNODES; i += 64) {
        LABG[i] = (int)s_lab[i];
        RNKG[i] = s_stamp[i];
    }
}

// ================= Phase A3: final arc compaction + remap (NT=1024) =================
__global__ __launch_bounds__(NT, 1)
void phaseA3(const int* __restrict__ U, const int* __restrict__ V,
             const int* __restrict__ LABG, const int* __restrict__ RNKG,
             const int* __restrict__ HAND, int* __restrict__ SC,
             int* __restrict__ TMP, float* __restrict__ out)
{
    __shared__ unsigned short l_lab[NNODES];
    __shared__ int l_rnk[NNODES];
    __shared__ int s_w[16];
    __shared__ int s_base[1];

    const int tid = threadIdx.x;
    for (int i = tid; i < NNODES; i += NT) {
        l_lab[i] = (unsigned short)LABG[i];
        l_rnk[i] = RNKG[i];
    }
    if (tid == 0) s_base[0] = 0;
    __syncthreads();

    const int E1 = HAND[0];
    const int K  = SC[0];
    const size_t obase = (size_t)K * 8192;

    for (int t = 0; t < E1; t += NT) {
        int e = t + tid, flag = 0, ru = 0, rv = 0;
        if (e < E1) {
            int uu = (int)l_lab[U[e]], vv = (int)l_lab[V[e]];
            if (uu != vv) { flag = 1; ru = l_rnk[uu]; rv = l_rnk[vv]; }
        }
        int tot;
        int off = blockScanExcl(flag, s_w, &tot);
        if (flag) {
            int r = s_base[0] + off;
            out[obase + (size_t)r] = (float)ru;
            TMP[r] = rv;
        }
        __syncthreads();
        if (tid == 0) s_base[0] += tot;
        __syncthreads();
    }
    const int Ef = s_base[0];
    if (tid == 0) SC[1] = Ef;
    for (int r = tid; r < Ef; r += NT)
        out[obase + (size_t)Ef + (size_t)r] = (float)TMP[r];
}

// ---------------- Phase B: END rows (Dv | mean) with fill indirection ----------------
__global__ __launch_bounds__(256, 4)
void phaseB(const float* __restrict__ x,
            const float* __restrict__ W1, const float* __restrict__ W2,
            const float* __restrict__ B1, const float* __restrict__ B2,
            const int* __restrict__ NBR, const int* __restrict__ SEL,
            const int* __restrict__ CNTS, const int* __restrict__ NST,
            const int* __restrict__ FIL, const int* __restrict__ SC,
            float* __restrict__ out)
{
    const int K = SC[0];
    const int k = blockIdx.x;
    if (k >= K) return;
    const int kk   = FIL[k];
    const int node = SEL[kk];
    const int cnt  = CNTS[kk];
    const int st   = NST[kk];
    const int tid  = threadIdx.x;
    const float4* x4 = (const float4*)x;

    float4 acc[4];
#pragma unroll
    for (int j = 0; j < 4; j++) acc[j] = make_float4(0.f, 0.f, 0.f, 0.f);

    for (int r = 0; r < cnt; ++r) {
        const float4* row = x4 + (size_t)NBR[st + r] * 1024;
#pragma unroll
        for (int j = 0; j < 4; j++) {
            float4 t = row[tid + j * 256];
            acc[j].x += t.x; acc[j].y += t.y; acc[j].z += t.z; acc[j].w += t.w;
        }
    }

    const float fc  = (float)cnt;
    const float inv = 1.0f / (float)(cnt > 1 ? cnt : 1);
    const float4* xr = x4 + (size_t)node * 1024;
    float4* o4 = (float4*)(out + (size_t)k * 8192);

#pragma unroll
    for (int j = 0; j < 4; j++) {
        int c = tid + j * 256;
        float4 w1 = ((const float4*)W1)[c], b1 = ((const float4*)B1)[c];
        float4 w2 = ((const float4*)W2)[c], b2 = ((const float4*)B2)[c];
        float4 xv = xr[c];
        float4 pd, pm;
        pd.x = xv.x * w2.x + b2.x;
        pd.y = xv.y * w2.y + b2.y;
        pd.z = xv.z * w2.z + b2.z;
        pd.w = xv.w * w2.w + b2.w;
        pm.x = (acc[j].x * w1.x + fc * b1.x) * inv;
        pm.y = (acc[j].y * w1.y + fc * b1.y) * inv;
        pm.z = (acc[j].z * w1.z + fc * b1.z) * inv;
        pm.w = (acc[j].w * w1.w + fc * b1.w) * inv;
        o4[c] = pd;
        o4[1024 + c] = pm;
    }
}

extern "C" void kernel_launch(void* const* d_in, const int* in_sizes, int n_in,
                              void* d_out, int out_size, void* d_ws, size_t ws_size,
                              hipStream_t stream)
{
    const float* x  = (const float*)d_in[0];
    const int*   ei = (const int*)d_in[1];
    const float* W1 = (const float*)d_in[2];
    const float* W2 = (const float*)d_in[3];
    const float* B1 = (const float*)d_in[4];
    const float* B2 = (const float*)d_in[5];
    const int E0 = in_sizes[1] / 2;

    char* w = (char*)d_ws;
    int* U = (int*)w;                         // [ECAP]
    int* V = U + ECAP;                        // [ECAP]
    unsigned int* BM = (unsigned int*)(V + ECAP);   // 2 MB bitmap (iter-0 only)
    int* OTH = (int*)BM;                      // [2*ECAP] static CSR other-endpoint
    int* NBR = OTH + 2 * ECAP;                // [2*ECAP]
    int* TMP = NBR + 2 * ECAP;                // [2*ECAP] A3 scratch
    char* meta = (char*)BM + (2u << 20);
    int* SEL   = (int*)meta;
    int* CNTS  = SEL  + NNODES;
    int* NST   = CNTS + NNODES;
    int* FIL   = NST  + NNODES;
    int* SC    = FIL  + NNODES;               // [16]
    int* ORDV  = SC   + 16;
    int* ROFFG = ORDV + NNODES;
    int* RENDG = ROFFG + NNODES;
    int* LABG  = RENDG + NNODES;
    int* RNKG  = LABG + NNODES;
    int* HAND  = RNKG + NNODES;               // [16]
    float* out = (float*)d_out;

    hipLaunchKernelGGL(phaseA1, dim3(1), dim3(NT), 0, stream,
                       ei, E0, U, V, BM, NBR, OTH, ORDV, ROFFG, RENDG, HAND);
    hipLaunchKernelGGL(phaseA2, dim3(1), dim3(64), 0, stream,
                       OTH, NBR, ORDV, ROFFG, RENDG, HAND,
                       SEL, CNTS, NST, FIL, SC, LABG, RNKG);
    hipLaunchKernelGGL(phaseA3, dim3(1), dim3(NT), 0, stream,
                       U, V, LABG, RNKG, HAND, SC, TMP, out);
    hipLaunchKernelGGL(phaseB, dim3(NNODES), dim3(256), 0, stream,
                       x, W1, W2, B1, B2, NBR, SEL, CNTS, NST, FIL, SC, out);
}